// Round 5
// baseline (316.374 us; speedup 1.0000x reference)
//
#include <hip/hip_runtime.h>

constexpr int B      = 4;
constexpr int T      = 4096;
constexpr int C      = 64;      // input dim
constexpr int H      = 64;      // head dim
constexpr int TILE   = 32;      // rows per compute block
constexpr int HALO   = 2;       // window radius
constexpr int HR     = TILE + 2 * HALO;   // 36 halo rows
constexpr int LS     = 68;      // LDS row stride (floats): 16B-aligned, breaks pow2 banks
constexpr int NT     = 256;     // threads per block
constexpr int NTILES = T / TILE;          // 128
constexpr int CBLOCKS = B * NTILES;       // 512 compute blocks

// ---------------- zero-fill kernel (LDS-FREE -> 32 waves/CU) ----------------
// Every fill we ran from inside the 56KB-LDS kernel (R0 inline, R1/R2 fill-role
// blocks, R4 branchless) hit ~2.4 TB/s: LDS caps occupancy at 8 waves/CU and
// streaming stores go queue-depth-bound. The harness's fillBufferAligned
// (8 VGPR, 0 LDS, 32 waves/CU) sustains 6.3-6.6 TB/s on the same buffer.
// This kernel replicates that config: 2048 blocks x 256 thr, 32 float4/thread,
// bare pointer-increment loop. 2048*256*32 == 16,777,216 == B*T*T/4 exactly.
constexpr int ZBLOCKS = 2048;
constexpr unsigned ZSTRIDE = (unsigned)ZBLOCKS * NT;   // 524288 float4s

__global__ __launch_bounds__(NT)
void zero_attn(float4* __restrict__ attn4)
{
    float4* __restrict__ p = attn4 + (size_t)blockIdx.x * NT + threadIdx.x;
    const float4 z = make_float4(0.f, 0.f, 0.f, 0.f);
#pragma unroll 8
    for (int k = 0; k < 32; ++k) { *p = z; p += ZSTRIDE; }
}

// ---------------- compute kernel (verified in R3, verbatim) ----------------
// LDS 36928 B/block; launch_bounds(256,4) keeps VGPRs <=128.
__global__ __launch_bounds__(NT, 4)
void sparse_attn_compute(const float* __restrict__ x,
                         const float* __restrict__ Wq,
                         const float* __restrict__ Wk,
                         const float* __restrict__ Wv,
                         float* __restrict__ out)
{
    __shared__ float sX[HR][LS];      // x halo rows (36 x 64 used)
    __shared__ float sW[C][LS];       // A = Wq^T@Wk, later Wv^T
    __shared__ float sU[TILE][LS];    // U = X@A, later Y = sum_d p_d x_{i+d}
    __shared__ float sS[TILE][8];     // probs (5 used per row)

    const int tid = threadIdx.x;
    const size_t attnBase = (size_t)B * T * H;

    const int b    = (int)(blockIdx.x / NTILES);
    const int tile = (int)(blockIdx.x % NTILES);
    const int row0 = tile * TILE;
    const float* xb = x + (size_t)b * T * C;

    // ---- P0: stage x halo; compute A = Wq^T @ Wk directly into sW ----
    // score(i,j) = q_i.k_j = x_i A x_j^T with A[c][c'] = sum_h Wq[h][c] Wk[h][c'].
    for (int s = tid; s < HR * (C / 4); s += NT) {
        const int lr = s >> 4;
        const int c4 = (s & 15) << 2;
        const int gr = row0 + lr - HALO;
        float4 v = make_float4(0.f, 0.f, 0.f, 0.f);
        if (gr >= 0 && gr < T) v = *(const float4*)(xb + (size_t)gr * C + c4);
        *(float4*)&sX[lr][c4] = v;
    }
    {
        // thread owns A[c][cp0..cp0+15]; Wq/Wk are 16 KB, L1/L2-hot.
        const int c   = tid >> 2;
        const int cp0 = (tid & 3) << 4;
        float acc[16];
#pragma unroll
        for (int j = 0; j < 16; ++j) acc[j] = 0.f;
#pragma unroll 4
        for (int h = 0; h < C; ++h) {
            const float  wq = Wq[h * 64 + c];
            const float4 k0 = *(const float4*)&Wk[h * 64 + cp0];
            const float4 k1 = *(const float4*)&Wk[h * 64 + cp0 + 4];
            const float4 k2 = *(const float4*)&Wk[h * 64 + cp0 + 8];
            const float4 k3 = *(const float4*)&Wk[h * 64 + cp0 + 12];
            acc[0]  = fmaf(wq, k0.x, acc[0]);  acc[1]  = fmaf(wq, k0.y, acc[1]);
            acc[2]  = fmaf(wq, k0.z, acc[2]);  acc[3]  = fmaf(wq, k0.w, acc[3]);
            acc[4]  = fmaf(wq, k1.x, acc[4]);  acc[5]  = fmaf(wq, k1.y, acc[5]);
            acc[6]  = fmaf(wq, k1.z, acc[6]);  acc[7]  = fmaf(wq, k1.w, acc[7]);
            acc[8]  = fmaf(wq, k2.x, acc[8]);  acc[9]  = fmaf(wq, k2.y, acc[9]);
            acc[10] = fmaf(wq, k2.z, acc[10]); acc[11] = fmaf(wq, k2.w, acc[11]);
            acc[12] = fmaf(wq, k3.x, acc[12]); acc[13] = fmaf(wq, k3.y, acc[13]);
            acc[14] = fmaf(wq, k3.z, acc[14]); acc[15] = fmaf(wq, k3.w, acc[15]);
        }
#pragma unroll
        for (int j = 0; j < 4; ++j)
            *(float4*)&sW[c][cp0 + 4 * j] =
                make_float4(acc[4*j], acc[4*j+1], acc[4*j+2], acc[4*j+3]);
    }
    __syncthreads();

    // ---- P1: U = X[tile] @ A  (all 256 threads: 2 rows x 4 cols each) ----
    {
        const int r0 = tid >> 4;            // 0..15 (rows r0, r0+16)
        const int h0 = (tid & 15) << 2;     // 0..60
        float acc[2][4];
#pragma unroll
        for (int k = 0; k < 2; ++k)
#pragma unroll
            for (int j = 0; j < 4; ++j) acc[k][j] = 0.f;
        for (int c4 = 0; c4 < C; c4 += 4) {
            const float4 xa = *(const float4*)&sX[r0 + HALO][c4];
            const float4 xc = *(const float4*)&sX[r0 + 16 + HALO][c4];
#pragma unroll
            for (int cc = 0; cc < 4; ++cc) {
                const float4 wv = *(const float4*)&sW[c4 + cc][h0];
                const float xs0 = (&xa.x)[cc];
                const float xs1 = (&xc.x)[cc];
                acc[0][0] = fmaf(xs0, wv.x, acc[0][0]);
                acc[0][1] = fmaf(xs0, wv.y, acc[0][1]);
                acc[0][2] = fmaf(xs0, wv.z, acc[0][2]);
                acc[0][3] = fmaf(xs0, wv.w, acc[0][3]);
                acc[1][0] = fmaf(xs1, wv.x, acc[1][0]);
                acc[1][1] = fmaf(xs1, wv.y, acc[1][1]);
                acc[1][2] = fmaf(xs1, wv.z, acc[1][2]);
                acc[1][3] = fmaf(xs1, wv.w, acc[1][3]);
            }
        }
        *(float4*)&sU[r0][h0]      = make_float4(acc[0][0], acc[0][1], acc[0][2], acc[0][3]);
        *(float4*)&sU[r0 + 16][h0] = make_float4(acc[1][0], acc[1][1], acc[1][2], acc[1][3]);
    }
    __syncthreads();

    // ---- P2: scores+softmax+band-write (tid<32); Wv^T staging (tid>=64) ----
    if (tid < TILE) {
        const int i  = tid;
        const int ig = row0 + i;
        float sc[5];
        float m = -__builtin_inff();
#pragma unroll
        for (int d = 0; d < 5; ++d) {
            const int jg = ig - HALO + d;
            float v = -__builtin_inff();
            if (jg >= 0 && jg < T) {
                float a = 0.f;
#pragma unroll
                for (int c4 = 0; c4 < C; c4 += 4) {
                    const float4 u  = *(const float4*)&sU[i][c4];
                    const float4 xk = *(const float4*)&sX[i + d][c4];
                    a += u.x * xk.x + u.y * xk.y + u.z * xk.z + u.w * xk.w;
                }
                v = a * 0.125f + (d > 2 ? 1.0f : 0.0f);   // scale C^-0.5; triu(+1) j>i
            }
            sc[d] = v;
            m = fmaxf(m, v);
        }
        float p[5];
        float sum = 0.f;
#pragma unroll
        for (int d = 0; d < 5; ++d) { p[d] = expf(sc[d] - m); sum += p[d]; }
        const float inv = 1.f / sum;
#pragma unroll
        for (int d = 0; d < 5; ++d) sS[i][d] = p[d] * inv;   // exp(-inf)=0 -> 0

        // band-containing float4 chunks, fully composed (zeros + probs).
        // Stream-ordered AFTER zero_attn, so overwriting is safe.
        float* rowp = out + attnBase + ((size_t)b * T + ig) * T;
        const int cLo = (ig - HALO > 0 ? ig - HALO : 0) >> 2;
        const int cHi = (ig + HALO < T - 1 ? ig + HALO : T - 1) >> 2;
        for (int cch = cLo; cch <= cHi; ++cch) {
            float vv[4];
#pragma unroll
            for (int q = 0; q < 4; ++q) {
                const int d = (cch << 2) + q - (ig - HALO);
                vv[q] = (d >= 0 && d < 5) ? sS[i][d] : 0.f;  // LDS runtime idx: fine
            }
            *(float4*)(rowp + (cch << 2)) = make_float4(vv[0], vv[1], vv[2], vv[3]);
        }
    }
    if (tid >= 64) {   // waves 1-3 stage Wv^T; wave0 stays on the score path
        for (int s = tid - 64; s < C * H; s += NT - 64)
            sW[s & 63][s >> 6] = Wv[s];
    }
    __syncthreads();

    // ---- P3: Y[i][c] = sum_d p_d * X[i+d][c]  (into sU; U is dead) ----
    {
        const int i  = tid >> 3;            // 0..31
        const int c0 = (tid & 7) << 3;      // 0..56, 8 floats per thread
        float y[8];
#pragma unroll
        for (int j = 0; j < 8; ++j) y[j] = 0.f;
#pragma unroll
        for (int d = 0; d < 5; ++d) {
            const float pd = sS[i][d];
            const float4 a  = *(const float4*)&sX[i + d][c0];
            const float4 b2 = *(const float4*)&sX[i + d][c0 + 4];
            y[0] = fmaf(pd, a.x, y[0]);  y[1] = fmaf(pd, a.y, y[1]);
            y[2] = fmaf(pd, a.z, y[2]);  y[3] = fmaf(pd, a.w, y[3]);
            y[4] = fmaf(pd, b2.x, y[4]); y[5] = fmaf(pd, b2.y, y[5]);
            y[6] = fmaf(pd, b2.z, y[6]); y[7] = fmaf(pd, b2.w, y[7]);
        }
        *(float4*)&sU[i][c0]     = make_float4(y[0], y[1], y[2], y[3]);
        *(float4*)&sU[i][c0 + 4] = make_float4(y[4], y[5], y[6], y[7]);
    }
    __syncthreads();

    // ---- P4: OP = Y @ Wv^T, stored straight to global ----
    {
        const int r0 = tid >> 4;
        const int h0 = (tid & 15) << 2;
        float acc[2][4];
#pragma unroll
        for (int k = 0; k < 2; ++k)
#pragma unroll
            for (int j = 0; j < 4; ++j) acc[k][j] = 0.f;
        for (int c4 = 0; c4 < C; c4 += 4) {
            const float4 ya = *(const float4*)&sU[r0][c4];
            const float4 yc = *(const float4*)&sU[r0 + 16][c4];
#pragma unroll
            for (int cc = 0; cc < 4; ++cc) {
                const float4 wv = *(const float4*)&sW[c4 + cc][h0];
                const float ys0 = (&ya.x)[cc];
                const float ys1 = (&yc.x)[cc];
                acc[0][0] = fmaf(ys0, wv.x, acc[0][0]);
                acc[0][1] = fmaf(ys0, wv.y, acc[0][1]);
                acc[0][2] = fmaf(ys0, wv.z, acc[0][2]);
                acc[0][3] = fmaf(ys0, wv.w, acc[0][3]);
                acc[1][0] = fmaf(ys1, wv.x, acc[1][0]);
                acc[1][1] = fmaf(ys1, wv.y, acc[1][1]);
                acc[1][2] = fmaf(ys1, wv.z, acc[1][2]);
                acc[1][3] = fmaf(ys1, wv.w, acc[1][3]);
            }
        }
        float* o = out + ((size_t)b * T + row0) * H;
        *(float4*)&o[(size_t)r0 * H + h0] =
            make_float4(acc[0][0], acc[0][1], acc[0][2], acc[0][3]);
        *(float4*)&o[(size_t)(r0 + 16) * H + h0] =
            make_float4(acc[1][0], acc[1][1], acc[1][2], acc[1][3]);
    }
}

extern "C" void kernel_launch(void* const* d_in, const int* in_sizes, int n_in,
                              void* d_out, int out_size, void* d_ws, size_t ws_size,
                              hipStream_t stream) {
    (void)in_sizes; (void)n_in; (void)d_ws; (void)ws_size; (void)out_size;
    const float* x  = (const float*)d_in[0];
    const float* Wq = (const float*)d_in[1];
    const float* Wk = (const float*)d_in[2];
    const float* Wv = (const float*)d_in[3];
    float* out = (float*)d_out;

    // 1) zero the attn region with a dedicated LDS-free kernel at fill-kernel
    //    occupancy (32 waves/CU), 2) compute + band/op writes, stream-ordered.
    float4* attn4 = (float4*)(out + (size_t)B * T * H);
    zero_attn<<<dim3(ZBLOCKS), dim3(NT), 0, stream>>>(attn4);
    sparse_attn_compute<<<dim3(CBLOCKS), dim3(NT), 0, stream>>>(x, Wq, Wk, Wv, out);
}